// Round 4
// baseline (2785.724 us; speedup 1.0000x reference)
//
#include <hip/hip_runtime.h>

#define BB   32
#define TT   2048
#define HH   256
#define G3   768      // 3*H
#define NVOC 18       // vocab rows (V+2)
#define NOUT 17       // head outputs (V+1)
#define LOGITS_ELEMS ((size_t)BB * TT * NOUT)

typedef _Float16 h2 __attribute__((ext_vector_type(2)));

__device__ __forceinline__ float bf1(unsigned short u){
  union{unsigned int i; float f;} v; v.i = ((unsigned int)u) << 16; return v.f;
}
__device__ __forceinline__ unsigned short f2bf(float f){
  union{float f; unsigned int i;} v; v.f = f;
  unsigned int lsb = (v.i >> 16) & 1u;
  v.i += 0x7fffu + lsb;               // round-to-nearest-even
  return (unsigned short)(v.i >> 16);
}
__device__ __forceinline__ float bflo(unsigned int u){
  union{unsigned int i; float f;} v; v.i = u << 16; return v.f;
}
__device__ __forceinline__ float bfhi(unsigned int u){
  union{unsigned int i; float f;} v; v.i = u & 0xffff0000u; return v.f;
}

__device__ __forceinline__ float ld1(const float* p, size_t i){ return p[i]; }
__device__ __forceinline__ float ld1(const unsigned short* p, size_t i){ return bf1(p[i]); }

// Device-side dtype detection: W_ih ~ uniform(-1/16,1/16). If the buffer is
// f32, low-half words decode as bf16 with random exponents -> some |v|>0.25.
__device__ __forceinline__ bool detect_f32(const void* W_ih_raw){
  const unsigned short* u = (const unsigned short*)W_ih_raw;
  bool big = false;
  #pragma unroll
  for (int i = 0; i < 64; i++){
    float v = bf1(u[i]);
    big |= !(v >= -0.25f && v <= 0.25f);
  }
  return big;
}

#if __has_builtin(__builtin_amdgcn_fdot2)
#define FDOT2(a,b,c) __builtin_amdgcn_fdot2((a),(b),(c),false)
#else
#define FDOT2(a,b,c) ((c) + (float)(a).x*(float)(b).x + (float)(a).y*(float)(b).y)
#endif

// ---------------------------------------------------------------------------
// k_prep: repack W_hh -> f16, layout matched to k_scan's coalesced float4
// reads: thread tid (u=tid>>1, q=tid&1) reads float4 f at Wp4[f*512+tid],
// holding h2 m=4f+c, m = g*64+kk  ->  W_hh[k0 + {0,1}][g*256+u], k0=q*128+2kk.
// ---------------------------------------------------------------------------
template<typename T>
__device__ __forceinline__ void prep_body(const T* W_hh, unsigned int* Wp){
  unsigned int e = blockIdx.x * 256 + threadIdx.x;    // [0, 98304)
  unsigned int c = e & 3, tmp = e >> 2;
  unsigned int tid = tmp & 511, f = tmp >> 9;
  unsigned int m = (f << 2) | c;
  unsigned int g = m >> 6, kk = m & 63;
  unsigned int u = tid >> 1, q = tid & 1;
  unsigned int col = g * 256 + u;
  unsigned int k0 = q * 128 + kk * 2;
  float lo = ld1(W_hh, (size_t)k0 * G3 + col);
  float hi = ld1(W_hh, (size_t)(k0 + 1) * G3 + col);
  h2 t; t.x = (_Float16)lo; t.y = (_Float16)hi;
  Wp[e] = __builtin_bit_cast(unsigned int, t);
}

__global__ __launch_bounds__(256) void k_prep(
    const void* __restrict__ W_hh, const void* __restrict__ W_ih,
    unsigned int* __restrict__ Wp)
{
  if (detect_f32(W_ih)) prep_body<float>((const float*)W_hh, Wp);
  else                  prep_body<unsigned short>((const unsigned short*)W_hh, Wp);
}

// ---------------------------------------------------------------------------
// k_proj: proj[v][j] = b_ih[j] + (j<512 ? b_hh[j] : 0) + sum_k e[v][k]W_ih[k][j]
// (b_hh folded for r,z gates; n's bias is scaled by r -> stays separate in bb)
// Block 0 also converts b_hh -> f32 bb[].
// ---------------------------------------------------------------------------
template<typename T>
__device__ __forceinline__ void proj_body(const T* embed, const T* W_ih,
                                          const T* b_ih, const T* b_hh,
                                          float* proj, float* bb){
  __shared__ float s_e[HH];
  int v = blockIdx.x, j = threadIdx.x;
  if (j < HH) s_e[j] = ld1(embed, (size_t)v * HH + j);
  if (v == 0) bb[j] = ld1(b_hh, (size_t)j);
  __syncthreads();
  float acc = ld1(b_ih, (size_t)j);
  if (j < 2 * HH) acc += ld1(b_hh, (size_t)j);
  #pragma unroll 8
  for (int k = 0; k < HH; k++)
    acc += s_e[k] * ld1(W_ih, (size_t)k * G3 + j);
  proj[(size_t)v * G3 + j] = acc;
}

__global__ __launch_bounds__(768) void k_proj(
    const void* __restrict__ embed, const void* __restrict__ W_ih,
    const void* __restrict__ b_ih, const void* __restrict__ b_hh,
    float* __restrict__ proj, float* __restrict__ bb)
{
  if (detect_f32(W_ih))
    proj_body<float>((const float*)embed, (const float*)W_ih,
                     (const float*)b_ih, (const float*)b_hh, proj, bb);
  else
    proj_body<unsigned short>((const unsigned short*)embed,
                              (const unsigned short*)W_ih,
                              (const unsigned short*)b_ih,
                              (const unsigned short*)b_hh, proj, bb);
}

// ---------------------------------------------------------------------------
// k_scan: one block per batch element, 512 threads. Pair (2u,2u+1) owns
// hidden unit u: all three gates, k split across the pair, shfl_xor combine.
// One barrier per step (ping-pong h). LDS padded to 83008 B so the backend's
// LDS-occupancy heuristic targets 1 block/CU = 2 waves/EU = 256-VGPR budget,
// keeping the 192-VGPR weight cache in registers (round-3 lesson: 84 = 512/6).
// ---------------------------------------------------------------------------
#define SPROJ_PAD 6656   // (13824+6656)*4 = 81920 B; + s_h bufs -> 83008 B

__global__ __launch_bounds__(512, 1) void k_scan(
    const int*          __restrict__ tokens,
    const unsigned int* __restrict__ Wp,     // prepped f16-pair weights
    const float*        __restrict__ bb,     // b_hh as f32 (n-gate bias)
    const void*         __restrict__ W_ih,   // dtype detection (betas store)
    const float*        __restrict__ proj,
    unsigned short*     __restrict__ outs,   // [B,T,H] bf16 scratch
    void*               __restrict__ d_out_base)
{
  __shared__ float s_proj[NVOC * G3 + SPROJ_PAD];
  // h as f16: 16 int4 (k 0..127) | 1 int4 pad | 16 int4 (k 128..255) = 544 B
  __shared__ __align__(16) unsigned int s_hA[136];
  __shared__ __align__(16) unsigned int s_hB[136];

  const bool f32m = detect_f32(W_ih);
  const int b   = blockIdx.x;
  const int tid = threadIdx.x;
  const int u   = tid >> 1;
  const int q   = tid & 1;

  for (int i = tid; i < NVOC * G3; i += 512) s_proj[i] = proj[i];

  // 192 h2 weights, coalesced float4 loads, constant indices -> VGPRs
  h2 w[192];
  {
    const float4* wp4 = (const float4*)Wp;
    #pragma unroll
    for (int f = 0; f < 48; f++) {
      float4 v = wp4[(size_t)f * 512 + tid];
      w[4*f+0] = __builtin_bit_cast(h2, v.x);
      w[4*f+1] = __builtin_bit_cast(h2, v.y);
      w[4*f+2] = __builtin_bit_cast(h2, v.z);
      w[4*f+3] = __builtin_bit_cast(h2, v.w);
    }
  }
  const float bbn = bb[2 * HH + u];

  if (tid < 136) s_hA[tid] = 0u;
  float h_old = 0.f;

  const int* tptr = tokens + (size_t)b * TT;
  int tok = tptr[0];
  unsigned short* orow   = outs + (size_t)b * TT * HH + u;                 // q==0
  unsigned short* brow_b = (unsigned short*)d_out_base + LOGITS_ELEMS
                           + (size_t)b * TT * HH + u;                      // q==1
  float*          brow_f = (float*)d_out_base + LOGITS_ELEMS
                           + (size_t)b * TT * HH + u;

  __syncthreads();

#define STEP(T, RB, WB)                                                      \
  {                                                                          \
    int tok_cur = tok;                                                       \
    tok = ((T) + 1 < TT) ? tptr[(T) + 1] : 0;                                \
    const float* pj = s_proj + tok_cur * G3;                                 \
    float gir = pj[u], giz = pj[HH + u], gin = pj[2*HH + u];                 \
    const int4* hp = (const int4*)(RB);                                      \
    float ar[4] = {0.f,0.f,0.f,0.f};                                         \
    float az[4] = {0.f,0.f,0.f,0.f};                                         \
    float an[4] = {0.f,0.f,0.f,0.f};                                         \
    _Pragma("unroll")                                                        \
    for (int i = 0; i < 16; i++) {                                           \
      int4 hv = hp[q * 17 + i];                                              \
      h2 x0 = __builtin_bit_cast(h2, hv.x);                                  \
      h2 x1 = __builtin_bit_cast(h2, hv.y);                                  \
      h2 x2 = __builtin_bit_cast(h2, hv.z);                                  \
      h2 x3 = __builtin_bit_cast(h2, hv.w);                                  \
      ar[0] = FDOT2(w[4*i+0],       x0, ar[0]);                              \
      ar[1] = FDOT2(w[4*i+1],       x1, ar[1]);                              \
      ar[2] = FDOT2(w[4*i+2],       x2, ar[2]);                              \
      ar[3] = FDOT2(w[4*i+3],       x3, ar[3]);                              \
      az[0] = FDOT2(w[64+4*i+0],    x0, az[0]);                              \
      az[1] = FDOT2(w[64+4*i+1],    x1, az[1]);                              \
      az[2] = FDOT2(w[64+4*i+2],    x2, az[2]);                              \
      az[3] = FDOT2(w[64+4*i+3],    x3, az[3]);                              \
      an[0] = FDOT2(w[128+4*i+0],   x0, an[0]);                              \
      an[1] = FDOT2(w[128+4*i+1],   x1, an[1]);                              \
      an[2] = FDOT2(w[128+4*i+2],   x2, an[2]);                              \
      an[3] = FDOT2(w[128+4*i+3],   x3, an[3]);                              \
    }                                                                        \
    float gr = (ar[0] + ar[1]) + (ar[2] + ar[3]);                            \
    float gz = (az[0] + az[1]) + (az[2] + az[3]);                            \
    float gn = (an[0] + an[1]) + (an[2] + an[3]);                            \
    gr += __shfl_xor(gr, 1);                                                 \
    gz += __shfl_xor(gz, 1);                                                 \
    gn += __shfl_xor(gn, 1);                                                 \
    float r = 1.f / (1.f + __expf(-(gir + gr)));                             \
    float z = 1.f / (1.f + __expf(-(giz + gz)));                             \
    float x = gin + r * (gn + bbn);                                          \
    x = fminf(fmaxf(x, -15.f), 15.f);                                        \
    float ex = __expf(2.f * x);                                              \
    float n = (ex - 1.f) / (ex + 1.f);                                       \
    float hn = (1.f - z) * n + z * h_old;                                    \
    h_old = hn;                                                              \
    if (q == 0) {                                                            \
      ((_Float16*)(WB))[(u >> 7) * 136 + (u & 127)] = (_Float16)hn;          \
      orow[(size_t)(T) * HH] = f2bf(hn);                                     \
    } else {                                                                 \
      if (f32m) brow_f[(size_t)(T) * HH] = z;                                \
      else      brow_b[(size_t)(T) * HH] = f2bf(z);                          \
    }                                                                        \
    __syncthreads();                                                         \
  }

  for (int t = 0; t < TT; t += 2) {
    STEP(t,     s_hA, s_hB)
    STEP(t + 1, s_hB, s_hA)
  }
#undef STEP
}

// ---------------------------------------------------------------------------
// k_head: logits = outs @ W_head + b_head
// ---------------------------------------------------------------------------
template<typename T>
__device__ __forceinline__ void stage_head(const T* W_head, const T* b_head,
                                           float* s_w, float* s_b, int tid){
  for (int i = tid; i < NOUT * HH; i += 256) {
    int o = i / HH, k = i - o * HH;
    s_w[i] = ld1(W_head, (size_t)k * NOUT + o);
  }
  if (tid < NOUT) s_b[tid] = ld1(b_head, (size_t)tid);
}

__global__ __launch_bounds__(256) void k_head(
    const unsigned short* __restrict__ outs,
    const void* __restrict__ W_head,
    const void* __restrict__ b_head,
    const void* __restrict__ W_ih,
    void* __restrict__ logits_out)
{
  __shared__ float s_w[NOUT * HH];
  __shared__ float s_b[NOUT];
  const bool f32m = detect_f32(W_ih);
  const int tid = threadIdx.x;

  if (f32m) stage_head<float>((const float*)W_head, (const float*)b_head,
                              s_w, s_b, tid);
  else      stage_head<unsigned short>((const unsigned short*)W_head,
                                       (const unsigned short*)b_head,
                                       s_w, s_b, tid);
  __syncthreads();

  size_t gid = (size_t)blockIdx.x * 256 + tid;
  if (gid >= LOGITS_ELEMS) return;
  int o = (int)(gid % NOUT);
  size_t row = gid / NOUT;

  const uint4* xp = (const uint4*)(outs + row * HH);
  const float* wv = s_w + o * HH;
  float a0 = 0.f, a1 = 0.f, a2 = 0.f, a3 = 0.f;
  #pragma unroll 8
  for (int kk = 0; kk < 32; kk++) {
    uint4 u = xp[kk];
    int kb = kk * 8;
    a0 += bflo(u.x) * wv[kb+0] + bfhi(u.x) * wv[kb+1];
    a1 += bflo(u.y) * wv[kb+2] + bfhi(u.y) * wv[kb+3];
    a2 += bflo(u.z) * wv[kb+4] + bfhi(u.z) * wv[kb+5];
    a3 += bflo(u.w) * wv[kb+6] + bfhi(u.w) * wv[kb+7];
  }
  float val = ((a0 + a1) + (a2 + a3)) + s_b[o];
  if (f32m) ((float*)logits_out)[gid] = val;
  else      ((unsigned short*)logits_out)[gid] = f2bf(val);
}

// ---------------------------------------------------------------------------
extern "C" void kernel_launch(void* const* d_in, const int* in_sizes, int n_in,
                              void* d_out, int out_size, void* d_ws, size_t ws_size,
                              hipStream_t stream)
{
  // inputs: tokens, embed, W_ih, W_hh, b_ih, b_hh, W_head, b_head
  const int* tokens = (const int*)d_in[0];
  const void* embed  = d_in[1];
  const void* W_ih   = d_in[2];
  const void* W_hh   = d_in[3];
  const void* b_ih   = d_in[4];
  const void* b_hh   = d_in[5];
  const void* W_head = d_in[6];
  const void* b_head = d_in[7];

  // ws: proj 55296 B | bb 3072 B | Wp 393216 B | outs 33.5 MB
  char* ws = (char*)d_ws;
  float*          proj = (float*)ws;
  float*          bb   = (float*)(ws + 55296);
  unsigned int*   Wp   = (unsigned int*)(ws + 55296 + 3072);
  unsigned short* outs = (unsigned short*)(ws + 55296 + 3072 + 393216);

  k_prep<<<384, 256, 0, stream>>>(W_hh, W_ih, Wp);
  k_proj<<<NVOC, G3, 0, stream>>>(embed, W_ih, b_ih, b_hh, proj, bb);
  k_scan<<<BB, 512, 0, stream>>>(tokens, Wp, bb, W_ih, proj, outs, d_out);
  k_head<<<(int)((LOGITS_ELEMS + 255) / 256), 256, 0, stream>>>(
      outs, W_head, b_head, W_ih, d_out);
}